// Round 10
// baseline (466.778 us; speedup 1.0000x reference)
//
#include <hip/hip_runtime.h>
#include <hip/hip_bf16.h>

// SlotMamba: B=64, K=256, D_MODEL=512, D_INNER=512, D_STATE=16, D_CONV=4, DT_RANK=32
// NTOK = 16384. Inputs f32, output f32. All three GEMMs bf16 MFMA 16x16x32.
// dt/xi/zs T-layout: [(b*512+d)*256 + t].
// Scan: chunked 3-phase (4 chunks x 64 t) using the affine composition
// h_end = P*h0 + L per chunk; P/L and h0 scratch live in d_out (written
// before k_fln overwrites it with the real output).
//
// ws layout (MB = 2^20):
//   xiT  [0,  32MB) f32 T-layout        gemm(in) -> xproj, scan1/3
//   xlnb [32, 48MB) bf16 [t][d]         ln -> gemm(in); head reused as xpwb/dtwb; region as yab
//   zsT  [48, 64MB) bf16 T-layout       gemm(in) -> scan3; head reused as WbO
//   dtT/o[64, 96MB) f32                 head = WbI; then dtT: xproj -> scan1/3; then o [t][d]
//   Bc   [96, 97MB), Cc [97, 98MB)      xproj -> scan1/3
// d_out scratch: PL [0,16MB) f32; h0buf [16,24MB) f32; final out overwrites.

#define NTOK 16384
#define DM   512

typedef __attribute__((ext_vector_type(8))) short bf16x8;
typedef __attribute__((ext_vector_type(4))) float f32x4;

__device__ __forceinline__ unsigned short f2bf(float f){
  unsigned int u = __float_as_uint(f);
  u = (u + 0x7fffu + ((u >> 16) & 1u)) >> 16;   // RNE
  return (unsigned short)u;
}
__device__ __forceinline__ float bfu(unsigned short p){ return __uint_as_float(((unsigned int)p) << 16); }
__device__ __forceinline__ unsigned int pk2(float a, float b){
  return (unsigned int)f2bf(a) | ((unsigned int)f2bf(b) << 16);
}
__device__ __forceinline__ float silu(float a){ return a / (1.f + __expf(-a)); }
// fast silu: v_rcp_f32 (~1 ulp) instead of the IEEE div expansion
__device__ __forceinline__ float silu_f(float a){
  return a * __builtin_amdgcn_rcpf(1.f + __expf(-a));
}

__device__ __forceinline__ void async_cp16(const unsigned short* g, unsigned short* l){
  __builtin_amdgcn_global_load_lds(
      (const __attribute__((address_space(1))) unsigned int*)g,
      (__attribute__((address_space(3))) unsigned int*)l, 16, 0, 0);
}

// ---------------- K0: f32 -> bf16 weight convert ----------------------------
__global__ __launch_bounds__(256) void k_cvtw(const float* __restrict__ W,
                                              unsigned short* __restrict__ Wb){
  int i = (blockIdx.x*256 + threadIdx.x)*8;
  float4 a = *(const float4*)(W+i);
  float4 b = *(const float4*)(W+i+4);
  uint4 st = { pk2(a.x,a.y), pk2(a.z,a.w), pk2(b.x,b.y), pk2(b.z,b.w) };
  *(uint4*)(Wb+i) = st;
}

// ---------------- K1: LayerNorm(slots) -> xlnb (bf16, [t][d]) ---------------
__global__ __launch_bounds__(64) void k_ln(const float* __restrict__ x,
                                           const float* __restrict__ g,
                                           const float* __restrict__ b,
                                           unsigned short* __restrict__ out){
  int tok  = blockIdx.x;
  int lane = threadIdx.x;
  const float* row = x + (size_t)tok*DM + lane*8;
  float4 r0 = *(const float4*)row;
  float4 r1 = *(const float4*)(row + 4);
  float v[8] = {r0.x,r0.y,r0.z,r0.w, r1.x,r1.y,r1.z,r1.w};
  float s = 0.f;
  #pragma unroll
  for (int i=0;i<8;i++) s += v[i];
  #pragma unroll
  for (int o=32;o;o>>=1) s += __shfl_xor(s, o, 64);
  float m = s * (1.0f/512.0f);
  float vs = 0.f;
  #pragma unroll
  for (int i=0;i<8;i++){ float d = v[i]-m; vs += d*d; }
  #pragma unroll
  for (int o=32;o;o>>=1) vs += __shfl_xor(vs, o, 64);
  float rs = rsqrtf(vs*(1.0f/512.0f) + 1e-5f);
  float4 g0 = *(const float4*)(g + lane*8);
  float4 g1 = *(const float4*)(g + lane*8 + 4);
  float4 b0 = *(const float4*)(b + lane*8);
  float4 b1 = *(const float4*)(b + lane*8 + 4);
  float gv[8] = {g0.x,g0.y,g0.z,g0.w, g1.x,g1.y,g1.z,g1.w};
  float bv[8] = {b0.x,b0.y,b0.z,b0.w, b1.x,b1.y,b1.z,b1.w};
  float o8[8];
  #pragma unroll
  for (int i=0;i<8;i++) o8[i] = (v[i]-m)*rs*gv[i] + bv[i];
  uint4 st = { pk2(o8[0],o8[1]), pk2(o8[2],o8[3]), pk2(o8[4],o8[5]), pk2(o8[6],o8[7]) };
  *(uint4*)(out + (size_t)tok*DM + lane*8) = st;
}

// ---------------- K2: 128x128-tile bf16-MFMA GEMM  C = A @ Wb^T -------------
__global__ __launch_bounds__(256) void k_gemm(const unsigned short* __restrict__ A,
                                              const unsigned short* __restrict__ Wb,
                                              float* __restrict__ out_f,
                                              unsigned short* __restrict__ out_b,
                                              int mode){
  __shared__ unsigned short As[2][128*32];
  __shared__ unsigned short Bs[2][128*32];
  int t0  = blockIdx.x * 128;
  int n0  = blockIdx.y * 128;
  int tid = threadIdx.x;
  int lane = tid & 63;
  int wv  = tid >> 6;
  int mw  = wv & 1, nw = wv >> 1;
  int m15 = lane & 15, quad = lane >> 4;

  int srow   = wv*32 + (lane >> 2);
  int schunk = ((lane & 3) ^ ((lane >> 3) & 3)) * 8;
  const unsigned short* gA = A  + (size_t)(t0 + srow)*DM + schunk;
  const unsigned short* gB = Wb + (size_t)(n0 + srow)*DM + schunk;
  unsigned short* asb0 = &As[0][(wv*32)*32];
  unsigned short* bsb0 = &Bs[0][(wv*32)*32];
  unsigned short* asb1 = &As[1][(wv*32)*32];
  unsigned short* bsb1 = &Bs[1][(wv*32)*32];

  async_cp16(gA,         asb0);
  async_cp16(gA + 16*DM, asb0 + 16*32);
  async_cp16(gB,         bsb0);
  async_cp16(gB + 16*DM, bsb0 + 16*32);

  f32x4 acc[4][4];
  #pragma unroll
  for (int rb=0;rb<4;rb++)
    #pragma unroll
    for (int cb=0;cb<4;cb++) acc[rb][cb] = (f32x4){0.f,0.f,0.f,0.f};

  int rdsw = (quad ^ ((m15 >> 1) & 3)) * 8;
  int cur = 0;
  for (int ks = 0; ks < 16; ks++){
    __syncthreads();
    if (ks < 15){
      const unsigned short* nA = gA + (ks+1)*32;
      const unsigned short* nB = gB + (ks+1)*32;
      unsigned short* na = cur ? asb0 : asb1;
      unsigned short* nb = cur ? bsb0 : bsb1;
      async_cp16(nA,         na);
      async_cp16(nA + 16*DM, na + 16*32);
      async_cp16(nB,         nb);
      async_cp16(nB + 16*DM, nb + 16*32);
    }
    bf16x8 af[4], bfr[4];
    #pragma unroll
    for (int rb=0;rb<4;rb++)
      af[rb] = *(const bf16x8*)&As[cur][(mw*64 + rb*16 + m15)*32 + rdsw];
    #pragma unroll
    for (int cb=0;cb<4;cb++)
      bfr[cb] = *(const bf16x8*)&Bs[cur][(nw*64 + cb*16 + m15)*32 + rdsw];
    #pragma unroll
    for (int rb=0;rb<4;rb++)
      #pragma unroll
      for (int cb=0;cb<4;cb++)
        acc[rb][cb] = __builtin_amdgcn_mfma_f32_16x16x32_bf16(af[rb], bfr[cb], acc[rb][cb], 0, 0, 0);
    cur ^= 1;
  }

  #pragma unroll
  for (int rb=0;rb<4;rb++){
    int tok0 = t0 + mw*64 + rb*16 + quad*4;
    int b    = tok0 >> 8;
    int tl0  = tok0 & 255;
    #pragma unroll
    for (int cb=0;cb<4;cb++){
      int nn = n0 + nw*64 + cb*16 + m15;
      f32x4 v = acc[rb][cb];
      if (mode == 0){
        if (nn < DM){
          *(f32x4*)(out_f + ((size_t)(b*DM + nn))*256 + tl0) = v;
        } else {
          uint2 z2 = { pk2(silu(v[0]), silu(v[1])), pk2(silu(v[2]), silu(v[3])) };
          *(uint2*)(out_b + ((size_t)(b*DM + (nn - DM)))*256 + tl0) = z2;
        }
      } else {
        #pragma unroll
        for (int r=0;r<4;r++) out_f[(size_t)(tok0+r)*DM + nn] = v[r];
      }
    }
  }
}

// -------- K3 (MFMA): conv4+silu -> bf16 A-tile; proj & dt via MFMA ----------
__global__ __launch_bounds__(256) void k_xproj(const float* __restrict__ xiT,
                                               const float* __restrict__ cw,
                                               const float* __restrict__ cb,
                                               const unsigned short* __restrict__ xpwb,
                                               const unsigned short* __restrict__ dtwb,
                                               const float* __restrict__ dtb,
                                               float* __restrict__ dtT,
                                               float* __restrict__ Bc,
                                               float* __restrict__ Cc){
  __shared__ unsigned short xcb[32*520];
  __shared__ unsigned short Bst[2][64*32];
  __shared__ unsigned short pjA[32*40];
  int t0  = blockIdx.x * 32;
  int b   = t0 >> 8;
  int tl0 = t0 & 255;
  int tid = threadIdx.x;
  int lane = tid & 63;
  int wv  = tid >> 6;
  int m15 = lane & 15, quad = lane >> 4;

  #pragma unroll
  for (int j=0;j<2;j++){
    int d = tid + 256*j;
    float4 cr = *(const float4*)(cw + d*4);
    float a0 = cb[d];
    const float* row = xiT + ((size_t)(b*DM + d))*256;
    float w[36];
    if (tl0 == 0){
      w[0]=w[1]=w[2]=w[3]=0.f;
      #pragma unroll
      for (int q2=0;q2<8;q2++){
        float4 v4 = *(const float4*)(row + q2*4);
        w[4+q2*4]=v4.x; w[5+q2*4]=v4.y; w[6+q2*4]=v4.z; w[7+q2*4]=v4.w;
      }
    } else {
      const float* p4 = row + tl0 - 4;
      #pragma unroll
      for (int q2=0;q2<9;q2++){
        float4 v4 = *(const float4*)(p4 + q2*4);
        w[q2*4]=v4.x; w[1+q2*4]=v4.y; w[2+q2*4]=v4.z; w[3+q2*4]=v4.w;
      }
    }
    #pragma unroll
    for (int t=0;t<32;t++){
      float a = a0 + w[t+1]*cr.x + w[t+2]*cr.y + w[t+3]*cr.z + w[t+4]*cr.w;
      xcb[t*520 + d] = f2bf(silu_f(a));
    }
  }

  int srow = wv*16 + (lane >> 2);
  int sch  = ((lane & 3) ^ ((lane >> 3) & 3)) * 8;
  async_cp16(xpwb + srow*DM + sch, &Bst[0][(wv*16)*32]);
  __syncthreads();

  int mt = wv & 1, ntp = wv >> 1;
  f32x4 pacc[2];
  pacc[0] = (f32x4){0.f,0.f,0.f,0.f};
  pacc[1] = (f32x4){0.f,0.f,0.f,0.f};
  int rdsw = (quad ^ ((m15 >> 1) & 3)) * 8;
  int cur = 0;
  for (int ks=0; ks<16; ks++){
    if (ks < 15)
      async_cp16(xpwb + srow*DM + (ks+1)*32 + sch, &Bst[cur^1][(wv*16)*32]);
    bf16x8 af = *(const bf16x8*)&xcb[(mt*16 + m15)*520 + ks*32 + quad*8];
    #pragma unroll
    for (int j2=0;j2<2;j2++){
      int nt = ntp*2 + j2;
      bf16x8 bfr = *(const bf16x8*)&Bst[cur][(nt*16 + m15)*32 + rdsw];
      pacc[j2] = __builtin_amdgcn_mfma_f32_16x16x32_bf16(af, bfr, pacc[j2], 0, 0, 0);
    }
    cur ^= 1;
    __syncthreads();
  }

  if (ntp == 0){
    #pragma unroll
    for (int j2=0;j2<2;j2++){
      int col = j2*16 + m15;
      #pragma unroll
      for (int r=0;r<4;r++)
        pjA[(mt*16 + quad*4 + r)*40 + col] = f2bf(pacc[j2][r]);
    }
  } else {
    #pragma unroll
    for (int j2=0;j2<2;j2++){
      int c = j2*16 + m15;
      #pragma unroll
      for (int r=0;r<4;r++){
        int tt = t0 + mt*16 + quad*4 + r;
        float v = pacc[j2][r];
        if (c < 16) Bc[(size_t)tt*16 + c] = v;
        else        Cc[(size_t)tt*16 + (c-16)] = v;
      }
    }
  }
  __syncthreads();

  bf16x8 adt = *(const bf16x8*)&pjA[(mt*16 + m15)*40 + quad*8];
  int nh = wv >> 1;
  #pragma unroll
  for (int j2=0;j2<16;j2++){
    int nn = (nh*16 + j2)*16 + m15;
    bf16x8 bfr = *(const bf16x8*)(dtwb + nn*32 + quad*8);
    f32x4 dacc = (f32x4){0.f,0.f,0.f,0.f};
    dacc = __builtin_amdgcn_mfma_f32_16x16x32_bf16(adt, bfr, dacc, 0, 0, 0);
    float bb = dtb[nn];
    f32x4 o;
    #pragma unroll
    for (int r=0;r<4;r++){
      float s = dacc[r] + bb;
      o[r] = (s > 20.f) ? s : log1pf(__expf(s));
    }
    *(f32x4*)(dtT + ((size_t)(b*DM + nn))*256 + tl0 + mt*16 + quad*4) = o;
  }
}

// ------ K4a: scan phase 1 — per-chunk P = prod(dA), L = local h_end ---------
// grid 2048 = 512 q-blocks x 4 chunks; 4 lanes x 4 states per (b,d).
__global__ __launch_bounds__(256) void k_scan1(const float* __restrict__ dtT,
                                               const float* __restrict__ xiT,
                                               const float* __restrict__ Bc,
                                               const float* __restrict__ cw,
                                               const float* __restrict__ cb,
                                               const float* __restrict__ Alog,
                                               float* __restrict__ PL){
  int tid = threadIdx.x;
  int sl  = tid & 3;
  int blk = blockIdx.x;
  int c   = blk & 3;
  int q   = (blk >> 2)*64 + (tid >> 2);
  int d   = q & 511;
  int b   = q >> 9;
  int tl0 = c*64;
  float4 Alr = *(const float4*)(Alog + d*16 + sl*4);
  float A0 = -__expf(Alr.x), A1 = -__expf(Alr.y);
  float A2 = -__expf(Alr.z), A3 = -__expf(Alr.w);
  float4 cr = *(const float4*)(cw + d*4);
  float cbv = cb[d];
  const float* dtp = dtT + (size_t)q*256;
  const float* xip = xiT + (size_t)q*256;
  const float* Bp  = Bc + (size_t)b*4096 + sl*4;
  float xm1, xm2, xm3;
  if (c == 0){ xm1 = xm2 = xm3 = 0.f; }
  else { float4 xw = *(const float4*)(xip + tl0 - 4); xm3 = xw.y; xm2 = xw.z; xm1 = xw.w; }
  float h0=0.f,h1=0.f,h2=0.f,h3=0.f;
  float p0=1.f,p1=1.f,p2=1.f,p3=1.f;
  #pragma unroll 2
  for (int t0=tl0; t0<tl0+64; t0+=4){
    float4 dt4 = *(const float4*)(dtp + t0);
    float4 xi4 = *(const float4*)(xip + t0);
    float xts[4] = {xi4.x, xi4.y, xi4.z, xi4.w};
    float dvs[4] = {dt4.x, dt4.y, dt4.z, dt4.w};
    #pragma unroll
    for (int r=0;r<4;r++){
      float4 Bv = *(const float4*)(Bp + (t0+r)*16);
      float a  = cbv + xm3*cr.x + xm2*cr.y + xm1*cr.z + xts[r]*cr.w;
      float u  = silu_f(a);
      float dv = dvs[r];
      float du = dv*u;
      float e0 = __expf(dv*A0), e1 = __expf(dv*A1);
      float e2 = __expf(dv*A2), e3 = __expf(dv*A3);
      h0 = e0*h0 + du*Bv.x;  p0 *= e0;
      h1 = e1*h1 + du*Bv.y;  p1 *= e1;
      h2 = e2*h2 + du*Bv.z;  p2 *= e2;
      h3 = e3*h3 + du*Bv.w;  p3 *= e3;
      xm3 = xm2; xm2 = xm1; xm1 = xts[r];
    }
  }
  float* p = PL + (((size_t)q*4 + c)*32 + sl*8);
  *(f32x4*)p       = (f32x4){p0,p1,p2,p3};
  *(f32x4*)(p + 4) = (f32x4){h0,h1,h2,h3};
}

// ------ K4b: compose chunk states: h0_{c+1} = L_c + P_c * h0_c --------------
__global__ __launch_bounds__(256) void k_scan2(const float* __restrict__ PL,
                                               float* __restrict__ h0buf){
  int i = blockIdx.x*256 + threadIdx.x;   // (q, sl)
  int q = i >> 2, sl = i & 3;
  const float* p = PL + ((size_t)q*4)*32 + sl*8;
  f32x4 h = (f32x4){0.f,0.f,0.f,0.f};
  #pragma unroll
  for (int c=0;c<4;c++){
    *(f32x4*)(h0buf + (((size_t)q*4 + c)*16 + sl*4)) = h;
    f32x4 P = *(const f32x4*)(p + c*32);
    f32x4 L = *(const f32x4*)(p + c*32 + 4);
    h = L + P*h;
  }
}

// ------ K4c: scan phase 3 — full recurrence per chunk, seeded with h0 -------
__global__ __launch_bounds__(256) void k_scan3(const float* __restrict__ dtT,
                                               const float* __restrict__ xiT,
                                               const unsigned short* __restrict__ zsT,
                                               const float* __restrict__ Bc,
                                               const float* __restrict__ Cc,
                                               const float* __restrict__ cw,
                                               const float* __restrict__ cb,
                                               const float* __restrict__ Alog,
                                               const float* __restrict__ Dpw,
                                               const float* __restrict__ h0buf,
                                               unsigned short* __restrict__ ya){
  int tid = threadIdx.x;
  int sl  = tid & 3;
  int blk = blockIdx.x;
  int c   = blk & 3;
  int q   = (blk >> 2)*64 + (tid >> 2);
  int d   = q & 511;
  int b   = q >> 9;
  int tl0 = c*64;
  float4 Alr = *(const float4*)(Alog + d*16 + sl*4);
  float A0 = -__expf(Alr.x), A1 = -__expf(Alr.y);
  float A2 = -__expf(Alr.z), A3 = -__expf(Alr.w);
  float Dv = Dpw[d];
  float4 cr = *(const float4*)(cw + d*4);
  float cbv = cb[d];
  const float* dtp = dtT + (size_t)q*256;
  const float* xip = xiT + (size_t)q*256;
  const unsigned short* zsp = zsT + (size_t)q*256;
  unsigned short* yap = ya + (size_t)b*256*DM + d;
  const float* Bp = Bc + (size_t)b*4096 + sl*4;
  const float* Cp = Cc + (size_t)b*4096 + sl*4;
  float xm1, xm2, xm3;
  if (c == 0){ xm1 = xm2 = xm3 = 0.f; }
  else { float4 xw = *(const float4*)(xip + tl0 - 4); xm3 = xw.y; xm2 = xw.z; xm1 = xw.w; }
  f32x4 hi = *(const f32x4*)(h0buf + (((size_t)q*4 + c)*16 + sl*4));
  float h0 = hi[0], h1 = hi[1], h2 = hi[2], h3 = hi[3];
  #pragma unroll 2
  for (int t0=tl0; t0<tl0+64; t0+=4){
    float4 dt4 = *(const float4*)(dtp + t0);
    float4 xi4 = *(const float4*)(xip + t0);
    uint2  zz  = *(const uint2*)(zsp + t0);
    float xts[4] = {xi4.x, xi4.y, xi4.z, xi4.w};
    float dvs[4] = {dt4.x, dt4.y, dt4.z, dt4.w};
    float zsf[4] = { bfu((unsigned short)zz.x), bfu((unsigned short)(zz.x>>16)),
                     bfu((unsigned short)zz.y), bfu((unsigned short)(zz.y>>16)) };
    #pragma unroll
    for (int r=0;r<4;r++){
      float4 Bv = *(const float4*)(Bp + (t0+r)*16);
      float4 Cv = *(const float4*)(Cp + (t0+r)*16);
      float a  = cbv + xm3*cr.x + xm2*cr.y + xm1*cr.z + xts[r]*cr.w;
      float u  = silu_f(a);
      float dv = dvs[r];
      float du = dv*u;
      h0 = __expf(dv*A0)*h0 + du*Bv.x;
      h1 = __expf(dv*A1)*h1 + du*Bv.y;
      h2 = __expf(dv*A2)*h2 + du*Bv.z;
      h3 = __expf(dv*A3)*h3 + du*Bv.w;
      float yy = h0*Cv.x + h1*Cv.y + h2*Cv.z + h3*Cv.w;
      yy += __shfl_xor(yy, 1);
      yy += __shfl_xor(yy, 2);
      if (sl == 0) yap[(size_t)(t0+r)*DM] = f2bf((yy + u*Dv) * zsf[r]);
      xm3 = xm2; xm2 = xm1; xm1 = xts[r];
    }
  }
}

// ---------------- K5: out = LayerNorm(o + slots) (f32) ----------------------
__global__ __launch_bounds__(64) void k_fln(const float* __restrict__ o,
                                            const float* __restrict__ resid,
                                            const float* __restrict__ g,
                                            const float* __restrict__ b,
                                            float* __restrict__ out){
  int tok  = blockIdx.x;
  int lane = threadIdx.x;
  const float* row = o     + (size_t)tok*DM + lane*8;
  const float* rr  = resid + (size_t)tok*DM + lane*8;
  float4 r0 = *(const float4*)row;
  float4 r1 = *(const float4*)(row + 4);
  float4 s0 = *(const float4*)rr;
  float4 s1 = *(const float4*)(rr + 4);
  float v[8] = {r0.x+s0.x, r0.y+s0.y, r0.z+s0.z, r0.w+s0.w,
                r1.x+s1.x, r1.y+s1.y, r1.z+s1.z, r1.w+s1.w};
  float s = 0.f;
  #pragma unroll
  for (int i=0;i<8;i++) s += v[i];
  #pragma unroll
  for (int o2=32;o2;o2>>=1) s += __shfl_xor(s, o2, 64);
  float m = s * (1.0f/512.0f);
  float vs = 0.f;
  #pragma unroll
  for (int i=0;i<8;i++){ float d = v[i]-m; vs += d*d; }
  #pragma unroll
  for (int o2=32;o2;o2>>=1) vs += __shfl_xor(vs, o2, 64);
  float rs = rsqrtf(vs*(1.0f/512.0f) + 1e-5f);
  float4 g0 = *(const float4*)(g + lane*8);
  float4 g1 = *(const float4*)(g + lane*8 + 4);
  float4 b0 = *(const float4*)(b + lane*8);
  float4 b1 = *(const float4*)(b + lane*8 + 4);
  float gv[8] = {g0.x,g0.y,g0.z,g0.w, g1.x,g1.y,g1.z,g1.w};
  float bv[8] = {b0.x,b0.y,b0.z,b0.w, b1.x,b1.y,b1.z,b1.w};
  float o8[8];
  #pragma unroll
  for (int i=0;i<8;i++) o8[i] = (v[i]-m)*rs*gv[i] + bv[i];
  float4* op = (float4*)(out + (size_t)tok*DM + lane*8);
  op[0] = make_float4(o8[0],o8[1],o8[2],o8[3]);
  op[1] = make_float4(o8[4],o8[5],o8[6],o8[7]);
}

extern "C" void kernel_launch(void* const* d_in, const int* in_sizes, int n_in,
                              void* d_out, int out_size, void* d_ws, size_t ws_size,
                              hipStream_t stream) {
  const float* slots     = (const float*)d_in[0];
  const float* ln_g      = (const float*)d_in[1];
  const float* ln_b      = (const float*)d_in[2];
  const float* in_proj_w = (const float*)d_in[3];
  const float* conv_w    = (const float*)d_in[4];
  const float* conv_b    = (const float*)d_in[5];
  const float* x_proj_w  = (const float*)d_in[6];
  const float* dt_proj_w = (const float*)d_in[7];
  const float* dt_proj_b = (const float*)d_in[8];
  const float* A_log     = (const float*)d_in[9];
  const float* Dp        = (const float*)d_in[10];
  const float* out_projw = (const float*)d_in[11];
  const float* fln_g     = (const float*)d_in[12];
  const float* fln_b     = (const float*)d_in[13];
  float* out = (float*)d_out;

  const size_t MB = 1024*1024;
  char* base = (char*)d_ws;
  float*          xiT  = (float*)(base);                    // [0,32MB)
  unsigned short* xlnb = (unsigned short*)(base + 32*MB);   // [32,48MB)
  unsigned short* yab  = xlnb;
  unsigned short* xpwb = xlnb;                              // 64KB (after gemm-in)
  unsigned short* dtwb = xlnb + 32768;                      // 32KB
  unsigned short* zsT  = (unsigned short*)(base + 48*MB);   // [48,64MB)
  unsigned short* WbO  = zsT;
  float*          dto  = (float*)(base + 64*MB);            // [64,96MB)
  unsigned short* WbI  = (unsigned short*)dto;
  float*          Bc   = (float*)(base + 96*MB);
  float*          Cc   = (float*)(base + 97*MB);

  // d_out scratch (overwritten by k_fln at the end):
  float* PL    = out;                                       // 16 MB
  float* h0buf = out + (size_t)4*1024*1024;                 // 8 MB

  k_ln   <<<NTOK,           64, 0, stream>>>(slots, ln_g, ln_b, xlnb);
  k_cvtw <<<256,           256, 0, stream>>>(in_proj_w, WbI);          // 1024x512
  k_gemm <<<dim3(128, 8),  256, 0, stream>>>(xlnb, WbI, xiT, zsT, 0);
  k_cvtw <<<16,            256, 0, stream>>>(x_proj_w, xpwb);          // 64x512
  k_cvtw <<<8,             256, 0, stream>>>(dt_proj_w, dtwb);         // 512x32
  k_xproj<<<NTOK/32,       256, 0, stream>>>(xiT, conv_w, conv_b, xpwb, dtwb, dt_proj_b,
                                             dto, Bc, Cc);
  k_scan1<<<2048,          256, 0, stream>>>(dto, xiT, Bc, conv_w, conv_b, A_log, PL);
  k_scan2<<<512,           256, 0, stream>>>(PL, h0buf);
  k_scan3<<<2048,          256, 0, stream>>>(dto, xiT, zsT, Bc, Cc, conv_w, conv_b, A_log, Dp,
                                             h0buf, yab);
  k_cvtw <<<128,           256, 0, stream>>>(out_projw, WbO);          // 512x512
  k_gemm <<<dim3(128, 4),  256, 0, stream>>>(yab, WbO, dto, (unsigned short*)0, 1);
  k_fln  <<<NTOK,           64, 0, stream>>>(dto, slots, fln_g, fln_b, out);
}